// Round 1
// 356.215 us; speedup vs baseline: 1.0066x; 1.0066x over previous
//
#include <hip/hip_runtime.h>
#include <cstdint>
#include <cstddef>

// Problem: B=4, S=4096, HID=1024, H=16, DH=64
//   qkv = query @ W^T + b    (M=16384, N=3072, K=1024)
//   per-position (b,s): scores = q(16x64) @ k^T /8 + mask(16x16); softmax; o = p @ v(16x64)
// Pipeline: cast fp32->bf16 (query, W) -> MFMA GEMM (bf16, fp32 acc, +bias, store bf16)
//           -> per-position attention (bf16 K/V staged via global_load_lds) -> out fp32.
//
// GEMM: 256x256 tile, BK=64, 8 waves (2M x 4N), 8-phase pipelined schedule with
// counted vmcnt (never 0 in the main loop).  A-fragment rows are interleaved
// (fragrow i -> i*32 + wm*16) so phase p consumes rows [64p, 64p+64) of the A tile;
// B fragments are fully register-resident from phase 0.  Stage schedule per window t:
//   p1: A(t+1).h1   p2: B(t+2).h0   p3: A(t+2).h0 + B(t+2).h1
// => every staged region's last read is >=2 barriers before its overwriting DMA issues
// (race-free by barrier separation), and exactly 6 loads are outstanding at each
// window boundary => s_waitcnt vmcnt(6) once per K-tile.  LDS tiles keep the proven
// 16B-chunk XOR swizzle (slot = chunk ^ (row&7)): measured 0 bank-conflict cycles.
// ws layout: Qb bf16 [16M el] @0 ; Wb bf16 [3M el] @33554432 ; QKVb bf16 [48M el] @39845888

typedef __attribute__((ext_vector_type(8))) short bf16x8;
typedef __attribute__((ext_vector_type(4))) float f32x4;

__device__ inline unsigned short f2bf(float f) {
  unsigned int i = __float_as_uint(f);
  i += 0x7fff + ((i >> 16) & 1);   // RNE
  return (unsigned short)(i >> 16);
}

__device__ inline void async16(const void* g, void* l) {
  __builtin_amdgcn_global_load_lds(
      (const __attribute__((address_space(1))) void*)g,
      (__attribute__((address_space(3))) void*)l, 16, 0, 0);
}

// unpack 8 packed bf16 -> 8 fp32
__device__ inline void unpack8(bf16x8 v, float* f) {
  union { bf16x8 s; unsigned int u[4]; } x; x.s = v;
  #pragma unroll
  for (int i = 0; i < 4; ++i) {
    f[2 * i]     = __uint_as_float(x.u[i] << 16);
    f[2 * i + 1] = __uint_as_float(x.u[i] & 0xffff0000u);
  }
}

// ---------------- cast fp32 -> bf16, 4 elems/thread ----------------
__global__ __launch_bounds__(256) void cast_kernel(const float* __restrict__ in,
                                                   unsigned short* __restrict__ out,
                                                   int n) {
  int i = (blockIdx.x * 256 + threadIdx.x) * 4;
  if (i >= n) return;
  float4 v = *(const float4*)(in + i);
  union { unsigned short u[4]; unsigned long long ll; } o;
  o.u[0] = f2bf(v.x); o.u[1] = f2bf(v.y); o.u[2] = f2bf(v.z); o.u[3] = f2bf(v.w);
  *(unsigned long long*)(out + i) = o.ll;
}

// ---------------- GEMM: C[M=16384][N=3072] = A[M][1024] * B[N][1024]^T + bias ----------------
#define GK 1024
#define GN 3072
__global__ __launch_bounds__(512, 2) void gemm_qkv(const unsigned short* __restrict__ A,
                                                   const unsigned short* __restrict__ Bm,
                                                   const float* __restrict__ bias,
                                                   unsigned short* __restrict__ C) {
  // double-buffered 256x64 tiles of A and B: 2 * 2 * 32 KiB = 128 KiB LDS
  __shared__ unsigned short As[2][256][64];
  __shared__ unsigned short Bs[2][256][64];

  // XCD-bijective swizzle (768 blocks % 8 == 0), n-fast within each XCD chunk:
  // each XCD touches 8 A-panels (4 MB) and streams the 6 MB B.
  const int bid = blockIdx.x;
  const int swz = (bid & 7) * 96 + (bid >> 3);
  const int m0 = (swz / 12) * 256;
  const int n0 = (swz % 12) * 256;

  const int tid  = threadIdx.x;
  const int lane = tid & 63;
  const int wave = tid >> 6;
  const int wm = wave & 1;        // 2 waves in M
  const int wn = wave >> 1;       // 4 waves in N
  const int fr = lane & 15;
  const int fq = lane >> 4;

  // staging geometry: slot = rho*512 + tid; row = slot>>3; chunk = (slot&7)^(row&7).
  // 8 lanes covering one row read a permuted-but-complete 128B segment: coalesced.
  const int r0 = tid >> 3;
  const int c0 = (tid & 7) ^ (r0 & 7);
  const unsigned short* gA = A  + (size_t)(m0 + r0) * GK + c0 * 8;
  const unsigned short* gB = Bm + (size_t)(n0 + r0) * GK + c0 * 8;
  const int ls0 = wave * 512;     // wave-uniform LDS element base (round 0); round 1: +4096

  // stage one 128-row half (2 DMA rounds) of tile tt into its buffer
#define STAGE_A(tt, hh) do {                                                   \
    unsigned short* lb_ = &As[(tt) & 1][(hh) * 128][0];                        \
    const unsigned short* g_ = gA + (size_t)(hh) * 128 * GK + (tt) * 64;       \
    async16(g_, lb_ + ls0);                                                    \
    async16(g_ + (size_t)64 * GK, lb_ + 4096 + ls0);                           \
  } while (0)
#define STAGE_B(tt, hh) do {                                                   \
    unsigned short* lb_ = &Bs[(tt) & 1][(hh) * 128][0];                        \
    const unsigned short* g_ = gB + (size_t)(hh) * 128 * GK + (tt) * 64;       \
    async16(g_, lb_ + ls0);                                                    \
    async16(g_ + (size_t)64 * GK, lb_ + 4096 + ls0);                           \
  } while (0)

  f32x4 acc[8][4] = {};

  // prologue: tile0 fully; tile1 all but A.h1 (that lands at W(0).p1) = 14 loads
  STAGE_A(0, 0); STAGE_A(0, 1); STAGE_B(0, 0); STAGE_B(0, 1);
  STAGE_B(1, 0); STAGE_A(1, 0); STAGE_B(1, 1);

  for (int t = 0; t < 16; ++t) {
    const int cur = t & 1;
    // boundary gate: tile t fully staged (6 newer loads stay in flight)
    if (t < 15) { asm volatile("s_waitcnt vmcnt(6)" ::: "memory"); }
    else        { asm volatile("s_waitcnt vmcnt(0)" ::: "memory"); }
    __builtin_amdgcn_s_barrier();
    __builtin_amdgcn_sched_barrier(0);

    bf16x8 bfr[4][2];
    #pragma unroll
    for (int p = 0; p < 4; ++p) {
      // ds-read this phase's A sub-slab (rows 64p..64p+63 via interleaved map)
      bf16x8 af[2][2];
      #pragma unroll
      for (int ii = 0; ii < 2; ++ii) {
        const int rA = (p * 2 + ii) * 32 + wm * 16 + fr;
        #pragma unroll
        for (int ks = 0; ks < 2; ++ks)
          af[ii][ks] = *(const bf16x8*)&As[cur][rA][((ks * 4 + fq) ^ (rA & 7)) * 8];
      }
      if (p == 0) {
        // all B fragments for the window -> registers (frees B LDS for overwrite at p2+)
        #pragma unroll
        for (int j = 0; j < 4; ++j) {
          const int rB = wn * 64 + j * 16 + fr;
          #pragma unroll
          for (int ks = 0; ks < 2; ++ks)
            bfr[j][ks] = *(const bf16x8*)&Bs[cur][rB][((ks * 4 + fq) ^ (rB & 7)) * 8];
        }
      }
      // prefetch staging (targets proven >=2 barriers past their last read)
      if (p == 1 && t + 1 < 16) { STAGE_A(t + 1, 1); }
      if (p == 2 && t + 2 < 16) { STAGE_B(t + 2, 0); }
      if (p == 3 && t + 2 < 16) { STAGE_A(t + 2, 0); STAGE_B(t + 2, 1); }

      __builtin_amdgcn_s_barrier();
      __builtin_amdgcn_sched_barrier(0);
      __builtin_amdgcn_s_setprio(1);
      #pragma unroll
      for (int ks = 0; ks < 2; ++ks)
        #pragma unroll
        for (int ii = 0; ii < 2; ++ii)
          #pragma unroll
          for (int j = 0; j < 4; ++j)
            acc[p * 2 + ii][j] = __builtin_amdgcn_mfma_f32_16x16x32_bf16(
                af[ii][ks], bfr[j][ks], acc[p * 2 + ii][j], 0, 0, 0);
      __builtin_amdgcn_s_setprio(0);
      __builtin_amdgcn_sched_barrier(0);
    }
  }
#undef STAGE_A
#undef STAGE_B

  // epilogue: bias + bf16 store (no barrier needed; all data in regs)
  #pragma unroll
  for (int j = 0; j < 4; ++j) {
    const int col = n0 + wn * 64 + j * 16 + fr;
    const float bc = bias[col];
    #pragma unroll
    for (int i = 0; i < 8; ++i) {
      const int rowb = m0 + i * 32 + wm * 16 + fq * 4;
      #pragma unroll
      for (int rr = 0; rr < 4; ++rr)
        C[(size_t)(rowb + rr) * GN + col] = f2bf(acc[i][j][rr] + bc);
    }
  }
}

// ---------------- per-position attention ----------------
// one wave per position; lane = h*4 + dg (h = lane>>2, dg = lane&3).
// K/V staged to LDS as bf16 via global_load_lds (wave-private region, no syncthreads).
__global__ __launch_bounds__(256) void attn_kernel(const unsigned short* __restrict__ QKV,
                                                   const float* __restrict__ mask,
                                                   float* __restrict__ out) {
  __shared__ unsigned short shKV[4][2048];   // per wave: K [0..1023], V [1024..2047]
  const int wave = threadIdx.x >> 6;
  const int lane = threadIdx.x & 63;
  const int pos = blockIdx.x * 4 + wave;

  const unsigned short* row = QKV + (size_t)pos * 3072;

  // ---- stage K+V (2048 bf16 = 4 KB) via 4 DMA chunks
  #pragma unroll
  for (int t = 0; t < 4; ++t)
    async16(&row[1024 + t * 512 + (size_t)lane * 8], &shKV[wave][t * 512]);

  // ---- q slice from global: row[lane*16 .. +16)  (coalesced 32B/lane)
  bf16x8 q0 = *(const bf16x8*)&row[lane * 16];
  bf16x8 q1 = *(const bf16x8*)&row[lane * 16 + 8];

  const int h = lane >> 2;
  const int dg = lane & 3;

  const float* mrow = mask + (size_t)pos * 256 + h * 16;
  float4 m4[4];
  #pragma unroll
  for (int t = 0; t < 4; ++t) m4[t] = *(const float4*)&mrow[t * 4];

  float q[16];
  unpack8(q0, q);
  unpack8(q1, q + 8);

  asm volatile("s_waitcnt vmcnt(0)" ::: "memory");

  float s[16];
  #pragma unroll
  for (int g = 0; g < 16; ++g) {
    const unsigned short* kp = &shKV[wave][g * 64 + dg * 16];
    float kf[16];
    unpack8(*(const bf16x8*)kp, kf);
    unpack8(*(const bf16x8*)(kp + 8), kf + 8);
    float acc = 0.f;
    #pragma unroll
    for (int d = 0; d < 16; ++d) acc += q[d] * kf[d];
    s[g] = acc;
  }
  #pragma unroll
  for (int g = 0; g < 16; ++g) {
    s[g] += __shfl_xor(s[g], 1);
    s[g] += __shfl_xor(s[g], 2);
  }

  const float* mp = (const float*)m4;
  float mx = -1e30f;
  #pragma unroll
  for (int g = 0; g < 16; ++g) {
    s[g] = s[g] * 0.125f + mp[g];
    mx = fmaxf(mx, s[g]);
  }
  float sum = 0.f;
  #pragma unroll
  for (int g = 0; g < 16; ++g) { s[g] = __expf(s[g] - mx); sum += s[g]; }
  float inv = 1.f / sum;

  float o[16];
  #pragma unroll
  for (int dd = 0; dd < 16; ++dd) o[dd] = 0.f;
  #pragma unroll
  for (int g = 0; g < 16; ++g) {
    const unsigned short* vp = &shKV[wave][1024 + g * 64 + dg * 16];
    float vf[16];
    unpack8(*(const bf16x8*)vp, vf);
    unpack8(*(const bf16x8*)(vp + 8), vf + 8);
    float p = s[g];
    #pragma unroll
    for (int dd = 0; dd < 16; ++dd) o[dd] += p * vf[dd];
  }

  float* op = out + (size_t)pos * 1024 + lane * 16;
  #pragma unroll
  for (int t = 0; t < 4; ++t) {
    float4 w;
    w.x = o[t * 4 + 0] * inv; w.y = o[t * 4 + 1] * inv;
    w.z = o[t * 4 + 2] * inv; w.w = o[t * 4 + 3] * inv;
    *(float4*)(op + t * 4) = w;
  }
}

extern "C" void kernel_launch(void* const* d_in, const int* in_sizes, int n_in,
                              void* d_out, int out_size, void* d_ws, size_t ws_size,
                              hipStream_t stream) {
  const float* query = (const float*)d_in[0];
  // d_in[1] (key) and d_in[2] (value) are unused by the reference.
  const float* mask  = (const float*)d_in[3];
  const float* Wqkv  = (const float*)d_in[4];
  const float* bqkv  = (const float*)d_in[5];
  float* out = (float*)d_out;

  unsigned short* qb   = (unsigned short*)d_ws;                                  // 16,777,216 el
  unsigned short* wb   = (unsigned short*)((char*)d_ws + 33554432);              //  3,145,728 el
  unsigned short* qkvb = (unsigned short*)((char*)d_ws + 39845888);              // 50,331,648 el

  cast_kernel<<<16384, 256, 0, stream>>>(query, qb, 16777216);
  cast_kernel<<<3072, 256, 0, stream>>>(Wqkv, wb, 3145728);

  gemm_qkv<<<768, 512, 0, stream>>>(qb, wb, bqkv, qkvb);

  attn_kernel<<<4096, 256, 0, stream>>>(qkvb, mask, out);
}

// Round 2
// 331.583 us; speedup vs baseline: 1.0813x; 1.0743x over previous
//
#include <hip/hip_runtime.h>
#include <cstdint>
#include <cstddef>

// Problem: B=4, S=4096, HID=1024, H=16, DH=64
//   qkv = query @ W^T + b    (M=16384, N=3072, K=1024)
//   per-position (b,s): scores = q(16x64) @ k^T /8 + mask(16x16); softmax; o = p @ v(16x64)
// Pipeline: cast fp32->bf16 (query, W) -> MFMA GEMM (bf16, fp32 acc, +bias, store bf16)
//           -> per-position attention (bf16 K/V staged via global_load_lds) -> out fp32.
//
// GEMM: 256x256 tile, BK=64, 8 waves (2M x 4N), 4-phase-per-K-tile pipelined schedule
// with counted vmcnt (never 0 in the main loop).  A-fragment rows are interleaved
// (fragrow i -> i*32 + wm*16) so phase p consumes A rows [64p, 64p+64); B fragments are
// fully register-resident after phase 0.  Stage schedule per window t:
//   p0: A(t+1).h1   p2: B(t+2).h0   p3: A(t+2).h0 + B(t+2).h1
// Leads (issue -> first consumer): A.h0 5 phases, A.h1 6, B.h0 6, B.h1 5 (>= HBM latency).
// Gates: boundary vmcnt(8) completes exactly through p3(t-2) = {A(t).h0,B(t).h0,B(t).h1};
//        mid-window vmcnt(8) before barrier p1 completes exactly A(t).h1 (its consumer
//        is p2).  Every overwriting DMA issues >= 1 full barrier after the overwritten
//        region's consuming MFMA cluster (race-free by barrier separation, not timing).
// LDS tiles keep the proven 16B-chunk XOR swizzle (slot = chunk ^ (row&7)): 0 conflicts.
// ws layout: Qb bf16 [16M el] @0 ; Wb bf16 [3M el] @33554432 ; QKVb bf16 [48M el] @39845888

typedef __attribute__((ext_vector_type(8))) short bf16x8;
typedef __attribute__((ext_vector_type(4))) float f32x4;

__device__ inline unsigned short f2bf(float f) {
  unsigned int i = __float_as_uint(f);
  i += 0x7fff + ((i >> 16) & 1);   // RNE
  return (unsigned short)(i >> 16);
}

__device__ inline void async16(const void* g, void* l) {
  __builtin_amdgcn_global_load_lds(
      (const __attribute__((address_space(1))) void*)g,
      (__attribute__((address_space(3))) void*)l, 16, 0, 0);
}

// unpack 8 packed bf16 -> 8 fp32
__device__ inline void unpack8(bf16x8 v, float* f) {
  union { bf16x8 s; unsigned int u[4]; } x; x.s = v;
  #pragma unroll
  for (int i = 0; i < 4; ++i) {
    f[2 * i]     = __uint_as_float(x.u[i] << 16);
    f[2 * i + 1] = __uint_as_float(x.u[i] & 0xffff0000u);
  }
}

// ---------------- cast fp32 -> bf16, 4 elems/thread ----------------
__global__ __launch_bounds__(256) void cast_kernel(const float* __restrict__ in,
                                                   unsigned short* __restrict__ out,
                                                   int n) {
  int i = (blockIdx.x * 256 + threadIdx.x) * 4;
  if (i >= n) return;
  float4 v = *(const float4*)(in + i);
  union { unsigned short u[4]; unsigned long long ll; } o;
  o.u[0] = f2bf(v.x); o.u[1] = f2bf(v.y); o.u[2] = f2bf(v.z); o.u[3] = f2bf(v.w);
  *(unsigned long long*)(out + i) = o.ll;
}

// ---------------- GEMM: C[M=16384][N=3072] = A[M][1024] * B[N][1024]^T + bias ----------------
#define GK 1024
#define GN 3072
__global__ __launch_bounds__(512, 2) void gemm_qkv(const unsigned short* __restrict__ A,
                                                   const unsigned short* __restrict__ Bm,
                                                   const float* __restrict__ bias,
                                                   unsigned short* __restrict__ C) {
  // double-buffered 256x64 tiles of A and B: 2 * 2 * 32 KiB = 128 KiB LDS
  __shared__ unsigned short As[2][256][64];
  __shared__ unsigned short Bs[2][256][64];

  // XCD-bijective swizzle (768 blocks % 8 == 0), n-fast within each XCD chunk:
  // each XCD touches 8 A-panels (4 MB) and streams the 6 MB B (L3-resident).
  const int bid = blockIdx.x;
  const int swz = (bid & 7) * 96 + (bid >> 3);
  const int m0 = (swz / 12) * 256;
  const int n0 = (swz % 12) * 256;

  const int tid  = threadIdx.x;
  const int lane = tid & 63;
  const int wave = tid >> 6;
  const int wm = wave & 1;        // 2 waves in M
  const int wn = wave >> 1;       // 4 waves in N
  const int fr = lane & 15;
  const int fq = lane >> 4;

  // staging geometry: slot = rho*512 + tid; row = slot>>3; chunk = (slot&7)^(row&7).
  // 8 lanes covering one row read a permuted-but-complete 128B segment: coalesced.
  const int r0 = tid >> 3;
  const int c0 = (tid & 7) ^ (r0 & 7);
  const unsigned short* gA = A  + (size_t)(m0 + r0) * GK + c0 * 8;
  const unsigned short* gB = Bm + (size_t)(n0 + r0) * GK + c0 * 8;
  const int ls0 = wave * 512;     // wave-uniform LDS element base (round 0); round 1: +4096

  // stage one 128-row half (2 DMA rounds) of tile tt into its buffer
#define STAGE_A(tt, hh) do {                                                   \
    unsigned short* lb_ = &As[(tt) & 1][(hh) * 128][0];                        \
    const unsigned short* g_ = gA + (size_t)(hh) * 128 * GK + (tt) * 64;       \
    async16(g_, lb_ + ls0);                                                    \
    async16(g_ + (size_t)64 * GK, lb_ + 4096 + ls0);                           \
  } while (0)
#define STAGE_B(tt, hh) do {                                                   \
    unsigned short* lb_ = &Bs[(tt) & 1][(hh) * 128][0];                        \
    const unsigned short* g_ = gB + (size_t)(hh) * 128 * GK + (tt) * 64;       \
    async16(g_, lb_ + ls0);                                                    \
    async16(g_ + (size_t)64 * GK, lb_ + 4096 + ls0);                           \
  } while (0)

  f32x4 acc[8][4] = {};

  // prologue: tile0 fully; tile1 all but A.h1 (that lands at W(0).p0) = 14 loads
  STAGE_A(0, 0); STAGE_A(0, 1); STAGE_B(0, 0); STAGE_B(0, 1);
  STAGE_B(1, 0); STAGE_A(1, 0); STAGE_B(1, 1);

  for (int t = 0; t < 16; ++t) {
    const int cur = t & 1;
    // boundary gate: completes exactly {A(t).h0, B(t).h0, B(t).h1} (issued >=5 phases ago)
    if (t == 0)       { asm volatile("s_waitcnt vmcnt(6)" ::: "memory"); }
    else if (t == 15) { asm volatile("s_waitcnt vmcnt(0)" ::: "memory"); }
    else              { asm volatile("s_waitcnt vmcnt(8)" ::: "memory"); }
    __builtin_amdgcn_s_barrier();
    __builtin_amdgcn_sched_barrier(0);

    bf16x8 bfr[4][2];
    #pragma unroll
    for (int p = 0; p < 4; ++p) {
      // ds-read this phase's A sub-slab (rows 64p..64p+63 via interleaved map)
      bf16x8 af[2][2];
      #pragma unroll
      for (int ii = 0; ii < 2; ++ii) {
        const int rA = (p * 2 + ii) * 32 + wm * 16 + fr;
        #pragma unroll
        for (int ks = 0; ks < 2; ++ks)
          af[ii][ks] = *(const bf16x8*)&As[cur][rA][((ks * 4 + fq) ^ (rA & 7)) * 8];
      }
      if (p == 0) {
        // all B fragments for the window -> registers (frees B LDS for overwrite at p2+)
        #pragma unroll
        for (int j = 0; j < 4; ++j) {
          const int rB = wn * 64 + j * 16 + fr;
          #pragma unroll
          for (int ks = 0; ks < 2; ++ks)
            bfr[j][ks] = *(const bf16x8*)&Bs[cur][rB][((ks * 4 + fq) ^ (rB & 7)) * 8];
        }
        // stage A(t+1).h1 into the other buffer (its last reader was MFMA p3 of t-1,
        // ordered by the boundary barrier).  Consumer: p2 of window t+1 -> 6-phase lead.
        if (t + 1 < 16) { STAGE_A(t + 1, 1); }
      }
      if (p == 1) {
        // mid-window gate: completes exactly A(t).h1 (consumer is p2's ds_reads,
        // made cross-wave-visible by barrier p1 below).
        asm volatile("s_waitcnt vmcnt(8)" ::: "memory");
      }
      if (p == 2 && t + 2 < 16) { STAGE_B(t + 2, 0); }                   // B dead since p0
      if (p == 3 && t + 2 < 16) { STAGE_A(t + 2, 0); STAGE_B(t + 2, 1); } // A.h0 dead since p1

      __builtin_amdgcn_s_barrier();
      __builtin_amdgcn_sched_barrier(0);
      __builtin_amdgcn_s_setprio(1);
      #pragma unroll
      for (int ks = 0; ks < 2; ++ks)
        #pragma unroll
        for (int ii = 0; ii < 2; ++ii)
          #pragma unroll
          for (int j = 0; j < 4; ++j)
            acc[p * 2 + ii][j] = __builtin_amdgcn_mfma_f32_16x16x32_bf16(
                af[ii][ks], bfr[j][ks], acc[p * 2 + ii][j], 0, 0, 0);
      __builtin_amdgcn_s_setprio(0);
      __builtin_amdgcn_sched_barrier(0);
    }
  }
#undef STAGE_A
#undef STAGE_B

  // epilogue: bias + bf16 store (no barrier needed; all data in regs).
  // i-outer / j / rr-inner: the two 32B halves of each 64B C-line are written
  // 4 stores apart (measured clean 98 MB WRITE_SIZE in this order; j-outer
  // measured 187 MB from partial-line RMW).
  #pragma unroll
  for (int i = 0; i < 8; ++i) {
    #pragma unroll
    for (int j = 0; j < 4; ++j) {
      const int col = n0 + wn * 64 + j * 16 + fr;
      const float bc = bias[col];
      const int rowb = m0 + i * 32 + wm * 16 + fq * 4;
      #pragma unroll
      for (int rr = 0; rr < 4; ++rr)
        C[(size_t)(rowb + rr) * GN + col] = f2bf(acc[i][j][rr] + bc);
    }
  }
}

// ---------------- per-position attention ----------------
// one wave per position; lane = h*4 + dg (h = lane>>2, dg = lane&3).
// K/V staged to LDS as bf16 via global_load_lds (wave-private region, no syncthreads).
__global__ __launch_bounds__(256) void attn_kernel(const unsigned short* __restrict__ QKV,
                                                   const float* __restrict__ mask,
                                                   float* __restrict__ out) {
  __shared__ unsigned short shKV[4][2048];   // per wave: K [0..1023], V [1024..2047]
  const int wave = threadIdx.x >> 6;
  const int lane = threadIdx.x & 63;
  const int pos = blockIdx.x * 4 + wave;

  const unsigned short* row = QKV + (size_t)pos * 3072;

  // ---- stage K+V (2048 bf16 = 4 KB) via 4 DMA chunks
  #pragma unroll
  for (int t = 0; t < 4; ++t)
    async16(&row[1024 + t * 512 + (size_t)lane * 8], &shKV[wave][t * 512]);

  // ---- q slice from global: row[lane*16 .. +16)  (coalesced 32B/lane)
  bf16x8 q0 = *(const bf16x8*)&row[lane * 16];
  bf16x8 q1 = *(const bf16x8*)&row[lane * 16 + 8];

  const int h = lane >> 2;
  const int dg = lane & 3;

  const float* mrow = mask + (size_t)pos * 256 + h * 16;
  float4 m4[4];
  #pragma unroll
  for (int t = 0; t < 4; ++t) m4[t] = *(const float4*)&mrow[t * 4];

  float q[16];
  unpack8(q0, q);
  unpack8(q1, q + 8);

  asm volatile("s_waitcnt vmcnt(0)" ::: "memory");

  float s[16];
  #pragma unroll
  for (int g = 0; g < 16; ++g) {
    const unsigned short* kp = &shKV[wave][g * 64 + dg * 16];
    float kf[16];
    unpack8(*(const bf16x8*)kp, kf);
    unpack8(*(const bf16x8*)(kp + 8), kf + 8);
    float acc = 0.f;
    #pragma unroll
    for (int d = 0; d < 16; ++d) acc += q[d] * kf[d];
    s[g] = acc;
  }
  #pragma unroll
  for (int g = 0; g < 16; ++g) {
    s[g] += __shfl_xor(s[g], 1);
    s[g] += __shfl_xor(s[g], 2);
  }

  const float* mp = (const float*)m4;
  float mx = -1e30f;
  #pragma unroll
  for (int g = 0; g < 16; ++g) {
    s[g] = s[g] * 0.125f + mp[g];
    mx = fmaxf(mx, s[g]);
  }
  float sum = 0.f;
  #pragma unroll
  for (int g = 0; g < 16; ++g) { s[g] = __expf(s[g] - mx); sum += s[g]; }
  float inv = 1.f / sum;

  float o[16];
  #pragma unroll
  for (int dd = 0; dd < 16; ++dd) o[dd] = 0.f;
  #pragma unroll
  for (int g = 0; g < 16; ++g) {
    const unsigned short* vp = &shKV[wave][1024 + g * 64 + dg * 16];
    float vf[16];
    unpack8(*(const bf16x8*)vp, vf);
    unpack8(*(const bf16x8*)(vp + 8), vf + 8);
    float p = s[g];
    #pragma unroll
    for (int dd = 0; dd < 16; ++dd) o[dd] += p * vf[dd];
  }

  float* op = out + (size_t)pos * 1024 + lane * 16;
  #pragma unroll
  for (int t = 0; t < 4; ++t) {
    float4 w;
    w.x = o[t * 4 + 0] * inv; w.y = o[t * 4 + 1] * inv;
    w.z = o[t * 4 + 2] * inv; w.w = o[t * 4 + 3] * inv;
    *(float4*)(op + t * 4) = w;
  }
}

extern "C" void kernel_launch(void* const* d_in, const int* in_sizes, int n_in,
                              void* d_out, int out_size, void* d_ws, size_t ws_size,
                              hipStream_t stream) {
  const float* query = (const float*)d_in[0];
  // d_in[1] (key) and d_in[2] (value) are unused by the reference.
  const float* mask  = (const float*)d_in[3];
  const float* Wqkv  = (const float*)d_in[4];
  const float* bqkv  = (const float*)d_in[5];
  float* out = (float*)d_out;

  unsigned short* qb   = (unsigned short*)d_ws;                                  // 16,777,216 el
  unsigned short* wb   = (unsigned short*)((char*)d_ws + 33554432);              //  3,145,728 el
  unsigned short* qkvb = (unsigned short*)((char*)d_ws + 39845888);              // 50,331,648 el

  cast_kernel<<<16384, 256, 0, stream>>>(query, qb, 16777216);
  cast_kernel<<<3072, 256, 0, stream>>>(Wqkv, wb, 3145728);

  gemm_qkv<<<768, 512, 0, stream>>>(qb, wb, bqkv, qkvb);

  attn_kernel<<<4096, 256, 0, stream>>>(qkvb, mask, out);
}